// Round 4
// baseline (838.871 us; speedup 1.0000x reference)
//
#include <hip/hip_runtime.h>
#include <math.h>

// C=48, DM=24, DIN=48, DS=8, DC=4, DTR=2, B=2, D=H=W=32, L=32768
#define LL   32768
#define NCH  1024          // scan chunks per sequence
#define LC   32            // chunk length
#define BL48 3145728       // B*48*L floats (one dir, planar) == 2*48*LL
#define ROW48(g,l) (((size_t)(g)*LL + (l))*48)
#define ROW16(g,l) (((size_t)(g)*LL + (l))*16)

__device__ __forceinline__ float sigmoidf_(float x){ return 1.0f/(1.0f+__expf(-x)); }
__device__ __forceinline__ float softplusf_(float x){ return (x > 20.0f) ? x : log1pf(__expf(x)); }

// ---------------------------------------------------------------------------
// Fused LN + in-proj + causal conv + silu + x-proj + dt(softplus).
// tile=64 positions, block=192, one direction per blockIdx.z.
// Phase 1: 2 threads/row split in-proj halves (x->LDS, z->global).
// Phase 2: 2 threads/position split d-channels (24 each); xd pair-reduced in LDS.
// Outputs row-major per position: dtb/xcb/zb: [g][l][48], BCB: [g][l][16],
// g = dir*2 + b. Backward written at flipped position.
// ---------------------------------------------------------------------------
extern "C" __global__ void __launch_bounds__(192)
k_inconv(const float* __restrict__ cur,
         const float* __restrict__ lng, const float* __restrict__ lnb,
         const float* __restrict__ in_w, const float* __restrict__ conv_w,
         const float* __restrict__ conv_b, const float* __restrict__ xproj_w,
         const float* __restrict__ dt_w, const float* __restrict__ dt_b,
         float* __restrict__ dtb, float* __restrict__ xcb, float* __restrict__ zb,
         float* __restrict__ BCB, int orient)
{
  __shared__ float xz[70][49];        // pre-conv x rows (3+64+3 halo)
  __shared__ float red[64][2][19];    // xd partials per (pos, half)
  const int t   = threadIdx.x;
  const int b   = blockIdx.y;
  const int dir = blockIdx.z;
  const int bs  = blockIdx.x * 64;
  const int j   = 2*orient + dir;
  const int g   = 2*dir + b;
  const int ch0 = dir*24;
  const float* iw = in_w + j*2304;   // (96,24)

  // ---- phase 1: LN + in-proj ----
  if (t < 140){
    const int half = (t < 70) ? 0 : 1;     // 0: x-half (e 0..47), 1: z-half (e 48..95)
    const int r = half ? (t-70) : t;
    const int l = bs - 3 + r;
    float u[24];
    bool valid = (l >= 0 && l < LL);
    if (valid) {
      const float* p = cur + (size_t)b*48*LL + l;
      float v[48]; float mu = 0.f;
      #pragma unroll
      for (int c2 = 0; c2 < 48; c2++){ v[c2] = p[(size_t)c2*LL]; mu += v[c2]; }
      mu *= (1.f/48.f);
      float var = 0.f;
      #pragma unroll
      for (int c2 = 0; c2 < 48; c2++){ float dd = v[c2]-mu; var += dd*dd; }
      float rstd = rsqrtf(var*(1.f/48.f) + 1e-5f);
      #pragma unroll
      for (int c2 = 0; c2 < 24; c2++)
        u[c2] = (v[ch0+c2]-mu)*rstd*lng[ch0+c2] + lnb[ch0+c2];
    } else {
      #pragma unroll
      for (int c2 = 0; c2 < 24; c2++) u[c2]=0.f;
    }
    if (half == 0){
      // x-half -> LDS rows
      for (int e = 0; e < 48; e++){
        float a = 0.f;
        #pragma unroll
        for (int d = 0; d < 24; d++) a += u[d]*iw[e*24+d];
        xz[r][e] = a;
      }
    } else if (r >= 3 && r < 67){
      // z-half -> global row (own rows only)
      const int pos = dir ? (LL-1-l) : l;
      float* zr = zb + ROW48(g, pos);
      for (int e0 = 48; e0 < 96; e0 += 4){
        float a[4];
        #pragma unroll
        for (int k = 0; k < 4; k++){
          float s = 0.f;
          #pragma unroll
          for (int d = 0; d < 24; d++) s += u[d]*iw[(e0+k)*24+d];
          a[k]=s;
        }
        *(float4*)(zr + (e0-48)) = make_float4(a[0],a[1],a[2],a[3]);
      }
    }
  }
  __syncthreads();

  // ---- phase 2: conv + silu + xc + x-proj + dt + B/C ----
  if (t < 128){
    const int p    = t & 63;
    const int half = t >> 6;          // d channels half*24 .. half*24+23
    const int d0   = half*24;
    const int l    = bs + p;
    const int pos  = dir ? (LL-1-l) : l;
    const float* cw = conv_w + j*192;   // (48,4)
    const float* cb = conv_b + j*48;
    const float* xw = xproj_w + j*864;  // (18,48)
    float xd[18];
    #pragma unroll
    for (int q = 0; q < 18; q++) xd[q]=0.f;
    float* xcr = xcb + ROW48(g, pos) + d0;
    for (int dd = 0; dd < 24; dd += 4){
      float vv[4];
      #pragma unroll
      for (int k = 0; k < 4; k++){
        int d = d0 + dd + k;
        float acc = cb[d];
        #pragma unroll
        for (int kk = 0; kk < 4; kk++){
          int rr = dir ? (p+6-kk) : (p+kk);
          acc += xz[rr][d] * cw[d*4+kk];
        }
        acc = acc * sigmoidf_(acc);   // silu
        vv[k] = acc;
        #pragma unroll
        for (int q = 0; q < 18; q++) xd[q] += acc*xw[q*48+d];
      }
      *(float4*)(xcr + dd) = make_float4(vv[0],vv[1],vv[2],vv[3]);
    }
    #pragma unroll
    for (int q = 0; q < 18; q++) red[p][half][q] = xd[q];
    __syncthreads();
    #pragma unroll
    for (int q = 0; q < 18; q++) xd[q] += red[p][1-half][q];

    // dt for own 24 channels
    const float* dw = dt_w + j*96;  // (48,2)
    const float* db = dt_b + j*48;
    float* dtr = dtb + ROW48(g, pos) + d0;
    for (int dd = 0; dd < 24; dd += 4){
      float vv[4];
      #pragma unroll
      for (int k = 0; k < 4; k++){
        int d = d0 + dd + k;
        vv[k] = softplusf_(xd[0]*dw[d*2] + xd[1]*dw[d*2+1] + db[d]);
      }
      *(float4*)(dtr + dd) = make_float4(vv[0],vv[1],vv[2],vv[3]);
    }
    // B/C row: half0 writes B (xd[2..9]), half1 writes C (xd[10..17])
    float* bc = BCB + ROW16(g, pos) + half*8;
    const int o = half*8;
    *(float4*)(bc+0) = make_float4(xd[2+o],xd[3+o],xd[4+o],xd[5+o]);
    *(float4*)(bc+4) = make_float4(xd[6+o],xd[7+o],xd[8+o],xd[9+o]);
  } else {
    __syncthreads();
  }
}

// ---------------------------------------------------------------------------
// Scan phase 1: lane = d (48 per stream), 4 streams per block (block=192).
// Per (g, chunk): P[s]=prod dA, S[s]=local scan from 0. PS layout [g][c][768]:
// P at [d*8+s], S at [384+d*8+s].
// ---------------------------------------------------------------------------
extern "C" __global__ void __launch_bounds__(192)
k_scan1(const float* __restrict__ dtb, const float* __restrict__ xcb,
        const float* __restrict__ BCB, const float* __restrict__ A_log,
        float* __restrict__ PS, int orient)
{
  const int d = threadIdx.x % 48;
  const int sid = blockIdx.x*4 + threadIdx.x/48;
  const int c = sid & (NCH-1);
  const int g = sid >> 10;          // dir*2 + b
  const int dir = g >> 1;
  const float* Al = A_log + (2*orient+dir)*384 + d*8;
  float A[8], P[8], S[8];
  #pragma unroll
  for (int s = 0; s < 8; s++){ A[s] = -__expf(Al[s]); P[s]=1.f; S[s]=0.f; }
  const float* pdt = dtb + ROW48(g, c*LC) + d;
  const float* pxc = xcb + ROW48(g, c*LC) + d;
  const float* pbc = BCB + ROW16(g, c*LC);
  #pragma unroll 4
  for (int j = 0; j < LC; j++){
    float dtv = pdt[(size_t)j*48];
    float xcv = pxc[(size_t)j*48];
    float4 b0 = *(const float4*)(pbc + (size_t)j*16);
    float4 b1 = *(const float4*)(pbc + (size_t)j*16 + 4);
    float Bs[8] = {b0.x,b0.y,b0.z,b0.w,b1.x,b1.y,b1.z,b1.w};
    float dx = dtv*xcv;
    #pragma unroll
    for (int s = 0; s < 8; s++){
      float dA = __expf(dtv*A[s]);
      P[s] *= dA;
      S[s] = S[s]*dA + dx*Bs[s];
    }
  }
  float* out = PS + ((size_t)g*NCH + c)*768 + d*8;
  *(float4*)(out)       = make_float4(P[0],P[1],P[2],P[3]);
  *(float4*)(out+4)     = make_float4(P[4],P[5],P[6],P[7]);
  *(float4*)(out+384)   = make_float4(S[0],S[1],S[2],S[3]);
  *(float4*)(out+388)   = make_float4(S[4],S[5],S[6],S[7]);
}

// ---------------------------------------------------------------------------
// Scan phase 2: per (g, state) sequential over chunks, 8-deep load pipelining.
// Overwrites S-slot with h at chunk start.
// ---------------------------------------------------------------------------
extern "C" __global__ void __launch_bounds__(256)
k_scan2(float* __restrict__ PS)
{
  int t = blockIdx.x*256 + threadIdx.x;
  if (t >= 1536) return;
  int g = t/384, st = t%384;
  float* base = PS + (size_t)g*NCH*768 + st;
  float h = 0.f;
  float Pc[8], Sc[8];
  #pragma unroll
  for (int k = 0; k < 8; k++){ Pc[k]=base[(size_t)k*768]; Sc[k]=base[(size_t)k*768+384]; }
  for (int c0 = 0; c0 < NCH; c0 += 8){
    float Pn[8], Sn[8];
    if (c0 + 8 < NCH){
      #pragma unroll
      for (int k = 0; k < 8; k++){
        Pn[k]=base[(size_t)(c0+8+k)*768];
        Sn[k]=base[(size_t)(c0+8+k)*768+384];
      }
    } else {
      #pragma unroll
      for (int k = 0; k < 8; k++){ Pn[k]=0.f; Sn[k]=0.f; }
    }
    #pragma unroll
    for (int k = 0; k < 8; k++){
      base[(size_t)(c0+k)*768+384] = h;
      h = fmaf(Pc[k], h, Sc[k]);
    }
    #pragma unroll
    for (int k = 0; k < 8; k++){ Pc[k]=Pn[k]; Sc[k]=Sn[k]; }
  }
}

// ---------------------------------------------------------------------------
// Scan phase 3 + gate + out-proj + residual, fused.
// Block = 192 threads = 4 pair-groups of 48 lanes (lane = d).
// Group pr handles fwd chunk cf = 4*bx+pr (plane g=b) AND bwd chunk
// NCH-1-cf (plane g=2+b) — both cover output l in [128*bx+32*pr, +32).
// Gated y staged in LDS; phase C does out-proj over both dirs + resid and
// writes sout planar [b][48][l].
// ---------------------------------------------------------------------------
extern "C" __global__ void __launch_bounds__(192)
k_scan3c(const float* __restrict__ dtb, const float* __restrict__ xcb,
         const float* __restrict__ zb, const float* __restrict__ BCB,
         const float* __restrict__ A_log, const float* __restrict__ Dp,
         const float* __restrict__ PS, const float* __restrict__ out_w,
         const float* __restrict__ resid, float* __restrict__ outp, int orient)
{
  __shared__ float yf[4][32][49];
  __shared__ float yb[4][32][49];
  const int t = threadIdx.x;
  const int d  = t % 48;
  const int pr = t / 48;
  const int b  = blockIdx.y;
  const int bx = blockIdx.x;
  const int cf = bx*4 + pr;
  const int cbk = NCH-1-cf;

  // ---- fwd scan (plane g=b, chunk cf) ----
  {
    const int g = b;
    const float* Al = A_log + (2*orient)*384 + d*8;
    const float* hp = PS + ((size_t)g*NCH + cf)*768 + 384 + d*8;
    float A[8], h[8];
    float4 h0 = *(const float4*)(hp);
    float4 h1 = *(const float4*)(hp+4);
    h[0]=h0.x; h[1]=h0.y; h[2]=h0.z; h[3]=h0.w;
    h[4]=h1.x; h[5]=h1.y; h[6]=h1.z; h[7]=h1.w;
    #pragma unroll
    for (int s = 0; s < 8; s++) A[s] = -__expf(Al[s]);
    const float Dpd = Dp[(2*orient)*48 + d];
    const float* pdt = dtb + ROW48(g, cf*LC) + d;
    const float* pxc = xcb + ROW48(g, cf*LC) + d;
    const float* pz  = zb  + ROW48(g, cf*LC) + d;
    const float* pbc = BCB + ROW16(g, cf*LC);
    for (int j2 = 0; j2 < LC; j2++){
      float dtv = pdt[(size_t)j2*48];
      float xcv = pxc[(size_t)j2*48];
      float zv  = pz [(size_t)j2*48];
      float4 b0 = *(const float4*)(pbc + (size_t)j2*16);
      float4 b1 = *(const float4*)(pbc + (size_t)j2*16 + 4);
      float4 c0 = *(const float4*)(pbc + (size_t)j2*16 + 8);
      float4 c1 = *(const float4*)(pbc + (size_t)j2*16 + 12);
      float Bs[8] = {b0.x,b0.y,b0.z,b0.w,b1.x,b1.y,b1.z,b1.w};
      float Cs[8] = {c0.x,c0.y,c0.z,c0.w,c1.x,c1.y,c1.z,c1.w};
      float dx = dtv*xcv;
      float y = 0.f;
      #pragma unroll
      for (int s = 0; s < 8; s++){
        float dA = __expf(dtv*A[s]);
        h[s] = h[s]*dA + dx*Bs[s];
        y += h[s]*Cs[s];
      }
      y += xcv*Dpd;
      yf[pr][j2][d] = y * (zv * sigmoidf_(zv));
    }
  }
  // ---- bwd scan (plane g=2+b, chunk cbk), stored output-reversed ----
  {
    const int g = 2 + b;
    const float* Al = A_log + (2*orient+1)*384 + d*8;
    const float* hp = PS + ((size_t)g*NCH + cbk)*768 + 384 + d*8;
    float A[8], h[8];
    float4 h0 = *(const float4*)(hp);
    float4 h1 = *(const float4*)(hp+4);
    h[0]=h0.x; h[1]=h0.y; h[2]=h0.z; h[3]=h0.w;
    h[4]=h1.x; h[5]=h1.y; h[6]=h1.z; h[7]=h1.w;
    #pragma unroll
    for (int s = 0; s < 8; s++) A[s] = -__expf(Al[s]);
    const float Dpd = Dp[(2*orient+1)*48 + d];
    const float* pdt = dtb + ROW48(g, cbk*LC) + d;
    const float* pxc = xcb + ROW48(g, cbk*LC) + d;
    const float* pz  = zb  + ROW48(g, cbk*LC) + d;
    const float* pbc = BCB + ROW16(g, cbk*LC);
    for (int j2 = 0; j2 < LC; j2++){
      float dtv = pdt[(size_t)j2*48];
      float xcv = pxc[(size_t)j2*48];
      float zv  = pz [(size_t)j2*48];
      float4 b0 = *(const float4*)(pbc + (size_t)j2*16);
      float4 b1 = *(const float4*)(pbc + (size_t)j2*16 + 4);
      float4 c0 = *(const float4*)(pbc + (size_t)j2*16 + 8);
      float4 c1 = *(const float4*)(pbc + (size_t)j2*16 + 12);
      float Bs[8] = {b0.x,b0.y,b0.z,b0.w,b1.x,b1.y,b1.z,b1.w};
      float Cs[8] = {c0.x,c0.y,c0.z,c0.w,c1.x,c1.y,c1.z,c1.w};
      float dx = dtv*xcv;
      float y = 0.f;
      #pragma unroll
      for (int s = 0; s < 8; s++){
        float dA = __expf(dtv*A[s]);
        h[s] = h[s]*dA + dx*Bs[s];
        y += h[s]*Cs[s];
      }
      y += xcv*Dpd;
      yb[pr][31-j2][d] = y * (zv * sigmoidf_(zv));   // bwd pos -> output-local slot
    }
  }
  __syncthreads();

  // ---- phase C: out-proj both dirs + residual, planar write ----
  if (t < 128){
    const int pair = t >> 5, pp = t & 31;
    const int l = bx*128 + t;
    const float* owf = out_w + (size_t)(2*orient)*1152;    // (24,48)
    const float* owb = out_w + (size_t)(2*orient+1)*1152;
    float of[24], ob[24];
    #pragma unroll
    for (int e = 0; e < 24; e++){ of[e]=0.f; ob[e]=0.f; }
    for (int dd = 0; dd < 48; dd++){
      float vf = yf[pair][pp][dd];
      float vb = yb[pair][pp][dd];
      #pragma unroll
      for (int e = 0; e < 24; e++){
        of[e] += vf*owf[e*48+dd];
        ob[e] += vb*owb[e*48+dd];
      }
    }
    const size_t pb = (size_t)b*48*LL + l;
    #pragma unroll
    for (int c2 = 0; c2 < 48; c2++){
      float val = (c2 < 24 ? of[c2] : ob[c2-24]) + resid[pb + (size_t)c2*LL];
      outp[pb + (size_t)c2*LL] = val;
    }
  }
}

// ---------------------------------------------------------------------------
// Digit-rotation transpose: out[t] = in[(t%32)*1024 + (t/32)] per plane,
// optionally + x. Used for l_i -> l_{i+1} and final -> physical (+x).
// ---------------------------------------------------------------------------
extern "C" __global__ void __launch_bounds__(256)
k_perm(const float* __restrict__ in, const float* __restrict__ xadd,
       float* __restrict__ out, int addx)
{
  __shared__ float t[32][33];
  const int q = blockIdx.y;            // plane: b*48 + c
  const float* ip = in + (size_t)q*LL;
  float* op = out + (size_t)q*LL;
  const int ab0 = blockIdx.x*32;
  const int tx = threadIdx.x & 31, ty = threadIdx.x >> 5;
  #pragma unroll
  for (int k = 0; k < 4; k++){
    int c = ty + 8*k;
    t[c][tx] = ip[(size_t)c*1024 + ab0 + tx];
  }
  __syncthreads();
  #pragma unroll
  for (int k = 0; k < 4; k++){
    int ab = ty + 8*k;
    float v = t[tx][ab];
    size_t o = (size_t)(ab0+ab)*32 + tx;
    if (addx) v += xadd[(size_t)q*LL + o];
    op[o] = v;
  }
}

extern "C" void kernel_launch(void* const* d_in, const int* in_sizes, int n_in,
                              void* d_out, int out_size, void* d_ws, size_t ws_size,
                              hipStream_t stream)
{
  const float* x       = (const float*)d_in[0];
  const float* ln_g    = (const float*)d_in[1];
  const float* ln_b    = (const float*)d_in[2];
  const float* in_w    = (const float*)d_in[3];
  const float* conv_w  = (const float*)d_in[4];
  const float* conv_b  = (const float*)d_in[5];
  const float* xproj_w = (const float*)d_in[6];
  const float* dt_w    = (const float*)d_in[7];
  const float* dt_b    = (const float*)d_in[8];
  const float* A_log   = (const float*)d_in[9];
  const float* Dp      = (const float*)d_in[10];
  const float* out_w   = (const float*)d_in[11];
  float* out = (float*)d_out;

  float* ws   = (float*)d_ws;
  float* dtb  = ws;                          // 4 planes * LL * 48
  float* xcb  = dtb + 2*(size_t)BL48;
  float* zbuf = xcb + 2*(size_t)BL48;
  float* BCB  = zbuf + 2*(size_t)BL48;       // 4*LL*16
  float* PS   = BCB + (size_t)4*LL*16;       // 4*NCH*768
  float* sout = PS  + (size_t)4*NCH*768;     // BL48
  float* curT = sout + (size_t)BL48;         // BL48

  for (int i = 0; i < 3; i++){
    const float* ip;
    if (i == 0) ip = x;
    else {
      k_perm<<<dim3(32, 96), 256, 0, stream>>>(sout, x, curT, 0);
      ip = curT;
    }
    k_inconv<<<dim3(LL/64, 2, 2), 192, 0, stream>>>(ip, ln_g + i*48, ln_b + i*48,
        in_w, conv_w, conv_b, xproj_w, dt_w, dt_b, dtb, xcb, zbuf, BCB, i);
    k_scan1<<<dim3(NCH), 192, 0, stream>>>(dtb, xcb, BCB, A_log, PS, i);
    k_scan2<<<dim3(6), 256, 0, stream>>>(PS);
    k_scan3c<<<dim3(NCH/4, 2), 192, 0, stream>>>(dtb, xcb, zbuf, BCB, A_log, Dp,
        PS, out_w, ip, sout, i);
  }
  k_perm<<<dim3(32, 96), 256, 0, stream>>>(sout, x, out, 1);
}

// Round 5
// 749.994 us; speedup vs baseline: 1.1185x; 1.1185x over previous
//
#include <hip/hip_runtime.h>
#include <math.h>

// C=48, DM=24, DIN=48, DS=8, DC=4, DTR=2, B=2, D=H=W=32, L=32768
#define LL   32768
#define NCH  1024          // scan chunks per sequence
#define LC   32            // chunk length
#define BL48 3145728       // B*48*L floats (one dir set, planar) == 2*48*LL
#define ROW48(g,l) (((size_t)(g)*LL + (l))*48)
#define ROW16(g,l) (((size_t)(g)*LL + (l))*16)

typedef unsigned short ushort_t;
typedef ushort_t ushort8 __attribute__((ext_vector_type(8)));

__device__ __forceinline__ float sigmoidf_(float x){ return 1.0f/(1.0f+__expf(-x)); }
__device__ __forceinline__ float softplusf_(float x){ return (x > 20.0f) ? x : log1pf(__expf(x)); }
__device__ __forceinline__ ushort_t f2bf(float f){
  union { float f; unsigned u; } v; v.f = f;
  unsigned r = v.u + 0x7FFFu + ((v.u >> 16) & 1u);
  return (ushort_t)(r >> 16);
}
__device__ __forceinline__ float bf2f(ushort_t h){
  union { unsigned u; float f; } v; v.u = ((unsigned)h) << 16;
  return v.f;
}

// ---------------------------------------------------------------------------
// Fused LN + in-proj + causal conv + silu + x-proj + dt(softplus).
// tile=64 positions, block=192, one direction per blockIdx.z.
// Outputs bf16 row-major per position: dtb/xcb/zb: [g][l][48], BCB: [g][l][16]
// (B 0..7, C 8..15), g = dir*2 + b. Backward written at flipped position.
// ---------------------------------------------------------------------------
extern "C" __global__ void __launch_bounds__(192)
k_inconv(const float* __restrict__ cur,
         const float* __restrict__ lng, const float* __restrict__ lnb,
         const float* __restrict__ in_w, const float* __restrict__ conv_w,
         const float* __restrict__ conv_b, const float* __restrict__ xproj_w,
         const float* __restrict__ dt_w, const float* __restrict__ dt_b,
         ushort_t* __restrict__ dtb, ushort_t* __restrict__ xcb,
         ushort_t* __restrict__ zb, ushort_t* __restrict__ BCB, int orient)
{
  __shared__ float xz[70][49];        // pre-conv x rows (3+64+3 halo)
  __shared__ float red[64][2][19];    // xd partials per (pos, half)
  const int t   = threadIdx.x;
  const int b   = blockIdx.y;
  const int dir = blockIdx.z;
  const int bs  = blockIdx.x * 64;
  const int j   = 2*orient + dir;
  const int g   = 2*dir + b;
  const int ch0 = dir*24;
  const float* iw = in_w + j*2304;   // (96,24)

  // ---- phase 1: LN + in-proj ----
  if (t < 140){
    const int half = (t < 70) ? 0 : 1;     // 0: x-half (e 0..47), 1: z-half (e 48..95)
    const int r = half ? (t-70) : t;
    const int l = bs - 3 + r;
    float u[24];
    if (l >= 0 && l < LL) {
      const float* p = cur + (size_t)b*48*LL + l;
      float v[48]; float mu = 0.f;
      #pragma unroll
      for (int c2 = 0; c2 < 48; c2++){ v[c2] = p[(size_t)c2*LL]; mu += v[c2]; }
      mu *= (1.f/48.f);
      float var = 0.f;
      #pragma unroll
      for (int c2 = 0; c2 < 48; c2++){ float dd = v[c2]-mu; var += dd*dd; }
      float rstd = rsqrtf(var*(1.f/48.f) + 1e-5f);
      #pragma unroll
      for (int c2 = 0; c2 < 24; c2++)
        u[c2] = (v[ch0+c2]-mu)*rstd*lng[ch0+c2] + lnb[ch0+c2];
    } else {
      #pragma unroll
      for (int c2 = 0; c2 < 24; c2++) u[c2]=0.f;
    }
    if (half == 0){
      // x-half -> LDS rows
      for (int e = 0; e < 48; e++){
        float a = 0.f;
        #pragma unroll
        for (int d = 0; d < 24; d++) a += u[d]*iw[e*24+d];
        xz[r][e] = a;
      }
    } else if (r >= 3 && r < 67){
      // z-half -> global bf16 row (own rows only)
      const int pos = dir ? (LL-1-l) : l;
      ushort_t* zr = zb + ROW48(g, pos);
      for (int e0 = 48; e0 < 96; e0 += 8){
        ushort8 v;
        #pragma unroll
        for (int k = 0; k < 8; k++){
          float s = 0.f;
          #pragma unroll
          for (int d = 0; d < 24; d++) s += u[d]*iw[(e0+k)*24+d];
          v[k] = f2bf(s);
        }
        *(ushort8*)(zr + (e0-48)) = v;
      }
    }
  }
  __syncthreads();

  // ---- phase 2: conv + silu + xc + x-proj + dt + B/C ----
  if (t < 128){
    const int p    = t & 63;
    const int half = t >> 6;          // d channels half*24 .. half*24+23
    const int d0   = half*24;
    const int l    = bs + p;
    const int pos  = dir ? (LL-1-l) : l;
    const float* cw = conv_w + j*192;   // (48,4)
    const float* cb = conv_b + j*48;
    const float* xw = xproj_w + j*864;  // (18,48)
    float xd[18];
    #pragma unroll
    for (int q = 0; q < 18; q++) xd[q]=0.f;
    float xcv[24];
    for (int dd = 0; dd < 24; dd++){
      int d = d0 + dd;
      float acc = cb[d];
      #pragma unroll
      for (int kk = 0; kk < 4; kk++){
        int rr = dir ? (p+6-kk) : (p+kk);
        acc += xz[rr][d] * cw[d*4+kk];
      }
      acc = acc * sigmoidf_(acc);   // silu
      xcv[dd] = acc;
      #pragma unroll
      for (int q = 0; q < 18; q++) xd[q] += acc*xw[q*48+d];
    }
    #pragma unroll
    for (int q = 0; q < 18; q++) red[p][half][q] = xd[q];
    // store xc (bf16, 3x ushort8)
    ushort_t* xcr = xcb + ROW48(g, pos) + d0;
    #pragma unroll
    for (int q8 = 0; q8 < 24; q8 += 8){
      ushort8 v;
      #pragma unroll
      for (int k = 0; k < 8; k++) v[k] = f2bf(xcv[q8+k]);
      *(ushort8*)(xcr + q8) = v;
    }
    __syncthreads();
    #pragma unroll
    for (int q = 0; q < 18; q++) xd[q] += red[p][1-half][q];

    // dt for own 24 channels
    const float* dw = dt_w + j*96;  // (48,2)
    const float* db = dt_b + j*48;
    ushort_t* dtr = dtb + ROW48(g, pos) + d0;
    #pragma unroll
    for (int q8 = 0; q8 < 24; q8 += 8){
      ushort8 v;
      #pragma unroll
      for (int k = 0; k < 8; k++){
        int d = d0 + q8 + k;
        v[k] = f2bf(softplusf_(xd[0]*dw[d*2] + xd[1]*dw[d*2+1] + db[d]));
      }
      *(ushort8*)(dtr + q8) = v;
    }
    // B/C row: half0 writes B (xd[2..9]), half1 writes C (xd[10..17])
    ushort_t* bc = BCB + ROW16(g, pos) + half*8;
    const int o = half*8;
    ushort8 v;
    #pragma unroll
    for (int k = 0; k < 8; k++) v[k] = f2bf(xd[2+o+k]);
    *(ushort8*)(bc) = v;
  } else {
    __syncthreads();
  }
}

// ---------------------------------------------------------------------------
// Scan phase 1: lane = d (48 per stream), 4 streams per block (block=192).
// Per (g, chunk): P[s]=prod dA, S[s]=local scan from 0. PS layout [g][c][768]
// fp32: P at [d*8+s], S at [384+d*8+s].
// ---------------------------------------------------------------------------
extern "C" __global__ void __launch_bounds__(192)
k_scan1(const ushort_t* __restrict__ dtb, const ushort_t* __restrict__ xcb,
        const ushort_t* __restrict__ BCB, const float* __restrict__ A_log,
        float* __restrict__ PS, int orient)
{
  const int d = threadIdx.x % 48;
  const int sid = blockIdx.x*4 + threadIdx.x/48;
  const int c = sid & (NCH-1);
  const int g = sid >> 10;          // dir*2 + b
  const int dir = g >> 1;
  const float* Al = A_log + (2*orient+dir)*384 + d*8;
  float A[8], P[8], S[8];
  #pragma unroll
  for (int s = 0; s < 8; s++){ A[s] = -__expf(Al[s]); P[s]=1.f; S[s]=0.f; }
  const ushort_t* pdt = dtb + ROW48(g, c*LC) + d;
  const ushort_t* pxc = xcb + ROW48(g, c*LC) + d;
  const ushort_t* pbc = BCB + ROW16(g, c*LC);
  #pragma unroll 4
  for (int j = 0; j < LC; j++){
    float dtv = bf2f(pdt[(size_t)j*48]);
    float xcv = bf2f(pxc[(size_t)j*48]);
    ushort8 br = *(const ushort8*)(pbc + (size_t)j*16);
    float dx = dtv*xcv;
    #pragma unroll
    for (int s = 0; s < 8; s++){
      float dA = __expf(dtv*A[s]);
      P[s] *= dA;
      S[s] = S[s]*dA + dx*bf2f(br[s]);
    }
  }
  float* out = PS + ((size_t)g*NCH + c)*768 + d*8;
  *(float4*)(out)       = make_float4(P[0],P[1],P[2],P[3]);
  *(float4*)(out+4)     = make_float4(P[4],P[5],P[6],P[7]);
  *(float4*)(out+384)   = make_float4(S[0],S[1],S[2],S[3]);
  *(float4*)(out+388)   = make_float4(S[4],S[5],S[6],S[7]);
}

// ---------------------------------------------------------------------------
// Scan phase 2, parallel: one 64-lane segment per (g,st) chain; each lane
// owns 16 consecutive chunks (local affine compose), Kogge-Stone shuffle scan
// of (P,S) across lanes, register replay writes h-at-chunk-start into S slot.
// 1536 chains * 64 lanes = 98304 threads = 384 blocks * 256.
// ---------------------------------------------------------------------------
extern "C" __global__ void __launch_bounds__(256)
k_scan2(float* __restrict__ PS)
{
  const int t = blockIdx.x*256 + threadIdx.x;
  const int chain = t >> 6;          // 0..1535
  const int lane  = t & 63;
  const int g  = chain / 384;
  const int st = chain % 384;
  float* base = PS + (size_t)g*NCH*768 + st;
  float P[16], S[16];
  const int c0 = lane*16;
  #pragma unroll
  for (int k = 0; k < 16; k++){
    P[k] = base[(size_t)(c0+k)*768];
    S[k] = base[(size_t)(c0+k)*768 + 384];
  }
  // local compose (apply chunks left->right): h_out = Pl*h_in + Sl
  float Pl = 1.f, Sl = 0.f;
  #pragma unroll
  for (int k = 0; k < 16; k++){ Sl = P[k]*Sl + S[k]; Pl = P[k]*Pl; }
  // inclusive Kogge-Stone over 64 lanes with affine composition
  float Pi = Pl, Si = Sl;
  #pragma unroll
  for (int off = 1; off < 64; off <<= 1){
    float Pp = __shfl_up(Pi, off);
    float Sp = __shfl_up(Si, off);
    if (lane >= off){ Si = Pi*Sp + Si; Pi = Pi*Pp; }
  }
  // h at start of this lane's chunks = inclusive result of previous lane (h0=0)
  float h = __shfl_up(Si, 1);
  if (lane == 0) h = 0.f;
  #pragma unroll
  for (int k = 0; k < 16; k++){
    base[(size_t)(c0+k)*768 + 384] = h;
    h = fmaf(P[k], h, S[k]);
  }
}

// ---------------------------------------------------------------------------
// Scan phase 3 + gate + out-proj + residual, fused.
// Block = 192 threads = 4 pair-groups of 48 lanes (lane = d).
// Group pr: fwd chunk cf = 4*bx+pr (g=b) AND bwd chunk NCH-1-cf (g=2+b),
// both covering output l in [128*bx+32*pr, +32). Gated y staged in LDS;
// phase C does out-proj over both dirs + resid, writes sout planar [b][48][l].
// ---------------------------------------------------------------------------
extern "C" __global__ void __launch_bounds__(192)
k_scan3c(const ushort_t* __restrict__ dtb, const ushort_t* __restrict__ xcb,
         const ushort_t* __restrict__ zb, const ushort_t* __restrict__ BCB,
         const float* __restrict__ A_log, const float* __restrict__ Dp,
         const float* __restrict__ PS, const float* __restrict__ out_w,
         const float* __restrict__ resid, float* __restrict__ outp, int orient)
{
  __shared__ float yf[4][32][49];
  __shared__ float yb[4][32][49];
  const int t = threadIdx.x;
  const int d  = t % 48;
  const int pr = t / 48;
  const int b  = blockIdx.y;
  const int bx = blockIdx.x;
  const int cf = bx*4 + pr;
  const int cbk = NCH-1-cf;

  // ---- fwd scan (plane g=b, chunk cf) ----
  {
    const int g = b;
    const float* Al = A_log + (2*orient)*384 + d*8;
    const float* hp = PS + ((size_t)g*NCH + cf)*768 + 384 + d*8;
    float A[8], h[8];
    float4 h0 = *(const float4*)(hp);
    float4 h1 = *(const float4*)(hp+4);
    h[0]=h0.x; h[1]=h0.y; h[2]=h0.z; h[3]=h0.w;
    h[4]=h1.x; h[5]=h1.y; h[6]=h1.z; h[7]=h1.w;
    #pragma unroll
    for (int s = 0; s < 8; s++) A[s] = -__expf(Al[s]);
    const float Dpd = Dp[(2*orient)*48 + d];
    const ushort_t* pdt = dtb + ROW48(g, cf*LC) + d;
    const ushort_t* pxc = xcb + ROW48(g, cf*LC) + d;
    const ushort_t* pz  = zb  + ROW48(g, cf*LC) + d;
    const ushort_t* pbc = BCB + ROW16(g, cf*LC);
    for (int j2 = 0; j2 < LC; j2++){
      float dtv = bf2f(pdt[(size_t)j2*48]);
      float xcv = bf2f(pxc[(size_t)j2*48]);
      float zv  = bf2f(pz [(size_t)j2*48]);
      ushort8 br = *(const ushort8*)(pbc + (size_t)j2*16);
      ushort8 cr = *(const ushort8*)(pbc + (size_t)j2*16 + 8);
      float dx = dtv*xcv;
      float y = 0.f;
      #pragma unroll
      for (int s = 0; s < 8; s++){
        float dA = __expf(dtv*A[s]);
        h[s] = h[s]*dA + dx*bf2f(br[s]);
        y += h[s]*bf2f(cr[s]);
      }
      y += xcv*Dpd;
      yf[pr][j2][d] = y * (zv * sigmoidf_(zv));
    }
  }
  // ---- bwd scan (plane g=2+b, chunk cbk), stored output-reversed ----
  {
    const int g = 2 + b;
    const float* Al = A_log + (2*orient+1)*384 + d*8;
    const float* hp = PS + ((size_t)g*NCH + cbk)*768 + 384 + d*8;
    float A[8], h[8];
    float4 h0 = *(const float4*)(hp);
    float4 h1 = *(const float4*)(hp+4);
    h[0]=h0.x; h[1]=h0.y; h[2]=h0.z; h[3]=h0.w;
    h[4]=h1.x; h[5]=h1.y; h[6]=h1.z; h[7]=h1.w;
    #pragma unroll
    for (int s = 0; s < 8; s++) A[s] = -__expf(Al[s]);
    const float Dpd = Dp[(2*orient+1)*48 + d];
    const ushort_t* pdt = dtb + ROW48(g, cbk*LC) + d;
    const ushort_t* pxc = xcb + ROW48(g, cbk*LC) + d;
    const ushort_t* pz  = zb  + ROW48(g, cbk*LC) + d;
    const ushort_t* pbc = BCB + ROW16(g, cbk*LC);
    for (int j2 = 0; j2 < LC; j2++){
      float dtv = bf2f(pdt[(size_t)j2*48]);
      float xcv = bf2f(pxc[(size_t)j2*48]);
      float zv  = bf2f(pz [(size_t)j2*48]);
      ushort8 br = *(const ushort8*)(pbc + (size_t)j2*16);
      ushort8 cr = *(const ushort8*)(pbc + (size_t)j2*16 + 8);
      float dx = dtv*xcv;
      float y = 0.f;
      #pragma unroll
      for (int s = 0; s < 8; s++){
        float dA = __expf(dtv*A[s]);
        h[s] = h[s]*dA + dx*bf2f(br[s]);
        y += h[s]*bf2f(cr[s]);
      }
      y += xcv*Dpd;
      yb[pr][31-j2][d] = y * (zv * sigmoidf_(zv));
    }
  }
  __syncthreads();

  // ---- phase C: out-proj both dirs + residual, planar write ----
  if (t < 128){
    const int pair = t >> 5, pp = t & 31;
    const int l = bx*128 + t;
    const float* owf = out_w + (size_t)(2*orient)*1152;    // (24,48)
    const float* owb = out_w + (size_t)(2*orient+1)*1152;
    float of[24], ob[24];
    #pragma unroll
    for (int e = 0; e < 24; e++){ of[e]=0.f; ob[e]=0.f; }
    for (int dd = 0; dd < 48; dd++){
      float vf = yf[pair][pp][dd];
      float vb = yb[pair][pp][dd];
      #pragma unroll
      for (int e = 0; e < 24; e++){
        of[e] += vf*owf[e*48+dd];
        ob[e] += vb*owb[e*48+dd];
      }
    }
    const size_t pb = (size_t)b*48*LL + l;
    #pragma unroll
    for (int c2 = 0; c2 < 48; c2++){
      float val = (c2 < 24 ? of[c2] : ob[c2-24]) + resid[pb + (size_t)c2*LL];
      outp[pb + (size_t)c2*LL] = val;
    }
  }
}

// ---------------------------------------------------------------------------
// Digit-rotation transpose: out[t] = in[(t%32)*1024 + (t/32)] per plane,
// optionally + x. Used for l_i -> l_{i+1} and final -> physical (+x).
// ---------------------------------------------------------------------------
extern "C" __global__ void __launch_bounds__(256)
k_perm(const float* __restrict__ in, const float* __restrict__ xadd,
       float* __restrict__ out, int addx)
{
  __shared__ float t[32][33];
  const int q = blockIdx.y;            // plane: b*48 + c
  const float* ip = in + (size_t)q*LL;
  float* op = out + (size_t)q*LL;
  const int ab0 = blockIdx.x*32;
  const int tx = threadIdx.x & 31, ty = threadIdx.x >> 5;
  #pragma unroll
  for (int k = 0; k < 4; k++){
    int c = ty + 8*k;
    t[c][tx] = ip[(size_t)c*1024 + ab0 + tx];
  }
  __syncthreads();
  #pragma unroll
  for (int k = 0; k < 4; k++){
    int ab = ty + 8*k;
    float v = t[tx][ab];
    size_t o = (size_t)(ab0+ab)*32 + tx;
    if (addx) v += xadd[(size_t)q*LL + o];
    op[o] = v;
  }
}

extern "C" void kernel_launch(void* const* d_in, const int* in_sizes, int n_in,
                              void* d_out, int out_size, void* d_ws, size_t ws_size,
                              hipStream_t stream)
{
  const float* x       = (const float*)d_in[0];
  const float* ln_g    = (const float*)d_in[1];
  const float* ln_b    = (const float*)d_in[2];
  const float* in_w    = (const float*)d_in[3];
  const float* conv_w  = (const float*)d_in[4];
  const float* conv_b  = (const float*)d_in[5];
  const float* xproj_w = (const float*)d_in[6];
  const float* dt_w    = (const float*)d_in[7];
  const float* dt_b    = (const float*)d_in[8];
  const float* A_log   = (const float*)d_in[9];
  const float* Dp      = (const float*)d_in[10];
  const float* out_w   = (const float*)d_in[11];
  float* out = (float*)d_out;

  char* w = (char*)d_ws;
  ushort_t* dtb  = (ushort_t*)w;  w += (size_t)4*LL*48*2;    // 12.6 MB bf16
  ushort_t* xcb  = (ushort_t*)w;  w += (size_t)4*LL*48*2;
  ushort_t* zbuf = (ushort_t*)w;  w += (size_t)4*LL*48*2;
  ushort_t* BCB  = (ushort_t*)w;  w += (size_t)4*LL*16*2;    // 4.2 MB
  float*    PS   = (float*)w;     w += (size_t)4*NCH*768*4;  // 12.6 MB fp32
  float*    sout = (float*)w;     w += (size_t)BL48*4;       // 12.6 MB fp32
  float*    curT = (float*)w;     w += (size_t)BL48*4;

  for (int i = 0; i < 3; i++){
    const float* ip;
    if (i == 0) ip = x;
    else {
      k_perm<<<dim3(32, 96), 256, 0, stream>>>(sout, x, curT, 0);
      ip = curT;
    }
    k_inconv<<<dim3(LL/64, 2, 2), 192, 0, stream>>>(ip, ln_g + i*48, ln_b + i*48,
        in_w, conv_w, conv_b, xproj_w, dt_w, dt_b, dtb, xcb, zbuf, BCB, i);
    k_scan1<<<dim3(NCH), 192, 0, stream>>>(dtb, xcb, BCB, A_log, PS, i);
    k_scan2<<<dim3(384), 256, 0, stream>>>(PS);
    k_scan3c<<<dim3(NCH/4, 2), 192, 0, stream>>>(dtb, xcb, zbuf, BCB, A_log, Dp,
        PS, out_w, ip, sout, i);
  }
  k_perm<<<dim3(32, 96), 256, 0, stream>>>(sout, x, out, 1);
}